// Round 3
// baseline (83.830 us; speedup 1.0000x reference)
//
#include <hip/hip_runtime.h>
#include <hip/hip_bf16.h>

// DynamicQAgent: B=4096 sessions, T=1000 steps. Sequential nonlinear scan in T,
// parallel in B (4096 lanes = 64 waves -> issue/latency-bound, 1 wave per CU).
//
// R3 changes vs R2 (which stalled ~100k cy on per-step LDS LUT reads):
//  1. Selection constants in REGISTERS via cndmask (R1 math, bit-identical).
//     No memory on the dependent chain.
//  2. No __syncthreads at all: single-wave blocks + in-order LDS pipe per wave
//     make staging RAW/WAR safe; avoids per-phase vmcnt(0) store-ack drains.
//  3. Staging stage[64 slots][65 sessions] float2: writes contiguous
//     (conflict-free), flush reads 520B stride = 4-way (b64 floor).
//  4. Prefetch next phase's code uint4s before compute (hide L2/HBM miss).

constexpr int BS = 4096;   // sessions
constexpr int TS = 1000;   // timesteps
constexpr int NW = 125;    // packed words per session (8 steps each)
constexpr int NG4 = 32;    // uint4 groups per session (128 words, padded)
constexpr int NPH = 16;    // phases (15 full x 8 words + 1 tail x 5 words)

__device__ __forceinline__ float sigmoidf_(float x) {
    return 1.0f / (1.0f + expf(-x));
}

struct Params {
    float k0, k1, k2, k3;
    float a0, a1, a2, a3;
    float g0, g1;
};

__device__ __forceinline__ Params load_params(const float* __restrict__ alpha_logits,
                                              const float* __restrict__ gamma_logits,
                                              const float* __restrict__ k_vals) {
    Params P;
    P.a0 = sigmoidf_(alpha_logits[0]);
    P.a1 = sigmoidf_(alpha_logits[1]);
    P.a2 = sigmoidf_(alpha_logits[2]);
    P.a3 = sigmoidf_(alpha_logits[3]);
    P.g0 = sigmoidf_(gamma_logits[0]);
    P.g1 = sigmoidf_(gamma_logits[1]);
    P.k0 = k_vals[0];
    P.k1 = k_vals[1];
    P.k2 = k_vals[2];
    P.k3 = k_vals[3];
    return P;
}

// one scan step; math identical to R1/R2 (absmax-verified)
__device__ __forceinline__ float2 step1(unsigned j, float& sL, float& sR, float& lam,
                                        const Params& P) {
    bool b0 = (j & 1u) != 0u;  // outcome == 0
    bool b1 = (j & 2u) != 0u;  // choice  == 0
    float k_lo = b0 ? P.k1 : P.k0;
    float k_hi = b0 ? P.k3 : P.k2;
    float a_lo = b0 ? P.a1 : P.a0;
    float a_hi = b0 ? P.a3 : P.a2;
    float gb   = b0 ? P.g1 : P.g0;
    float kj   = b1 ? k_hi : k_lo;
    float kjR  = b1 ? k_lo : k_hi;
    float aj   = b1 ? a_hi : a_lo;
    float ajR  = b1 ? a_lo : a_hi;
    float dL = kj - sL;           // old state
    float dR = kjR - sR;
    float v  = b1 ? dR : dL;      // gdiffs[j]
    sL = fmaf(dL * aj, lam, sL);
    sR = fmaf(dR * ajR, lam, sR);
    lam = fmaf(fabsf(v) - lam, gb, lam);
    return make_float2(sL, sR);
}

// --- pass 1: pack 8 steps (24 floats = 6 float4) into one u32 of 2-bit codes.
// Layout: uint4 index (w>>2)*BS + b  (i.e. [group][session][4 words]).
__global__ __launch_bounds__(256) void pack_kernel(const float* __restrict__ inp,
                                                   unsigned int* __restrict__ packed) {
    int tid = blockIdx.x * blockDim.x + threadIdx.x;
    if (tid >= BS * NW) return;
    int b = tid / NW;
    int w = tid - b * NW;
    const float4* p = reinterpret_cast<const float4*>(inp + (size_t)b * (3 * TS) + (size_t)w * 24);
    float4 q0 = p[0], q1 = p[1], q2 = p[2], q3 = p[3], q4 = p[4], q5 = p[5];
    float c[8] = {q0.x, q0.w, q1.z, q2.y, q3.x, q3.w, q4.z, q5.y};
    float o[8] = {q0.z, q1.y, q2.x, q2.w, q3.z, q4.y, q5.x, q5.w};
    unsigned word = 0;
#pragma unroll
    for (int i = 0; i < 8; ++i) {
        unsigned j = ((c[i] == 0.0f) ? 2u : 0u) | ((o[i] == 0.0f) ? 1u : 0u);
        word |= j << (2 * i);
    }
    packed[(size_t)(w >> 2) * (BS * 4) + (size_t)b * 4 + (w & 3)] = word;
}

// --- pass 2: scan. One wave (64 threads) per block, 64 blocks. Thread=session.
__global__ __launch_bounds__(64) void scan3(const uint4* __restrict__ packed4,
                                            const float* __restrict__ alpha_logits,
                                            const float* __restrict__ gamma_logits,
                                            const float* __restrict__ k_vals,
                                            float* __restrict__ out) {
    // [slot 0..63][session 0..63 + pad] : write conflict-free, read 4-way floor
    __shared__ float2 stage[64][65];

    const int l = threadIdx.x;
    const int b = blockIdx.x * 64 + l;
    const Params P = load_params(alpha_logits, gamma_logits, k_vals);

    float sL = 0.0f, sR = 0.0f, lam = 0.5f;
    const uint4* pp = packed4 + b;

    uint4 wa = pp[0];
    uint4 wb = pp[(size_t)BS];

    for (int f = 0; f < NPH; ++f) {
        // prefetch next phase's codes (wrap at end; wrapped values unused)
        const int gn = 2 * ((f + 1) & (NPH - 1));
        uint4 na = pp[(size_t)gn * BS];
        uint4 nb = pp[(size_t)(gn + 1) * BS];

        const unsigned words[8] = {wa.x, wa.y, wa.z, wa.w, wb.x, wb.y, wb.z, wb.w};

        if (f != NPH - 1) {
#pragma unroll
            for (int q = 0; q < 8; ++q) {
                unsigned w = words[q];
#pragma unroll
                for (int i = 0; i < 8; ++i) {
                    stage[q * 8 + i][l] = step1((w >> (2 * i)) & 3u, sL, sR, lam, P);
                }
            }
        } else {
#pragma unroll
            for (int q = 0; q < 5; ++q) {   // tail: 5 words = 40 steps
                unsigned w = words[q];
#pragma unroll
                for (int i = 0; i < 8; ++i) {
                    stage[q * 8 + i][l] = step1((w >> (2 * i)) & 3u, sL, sR, lam, P);
                }
            }
        }

        asm volatile("" ::: "memory");  // keep source order; HW LDS pipe is in-order

        // flush: iteration s = session; lane l supplies slot l (step f*64+l)
        const int nslots = (f == NPH - 1) ? 40 : 64;
        const bool act = l < nslots;
        float* ob = out + ((size_t)blockIdx.x * 64) * (2 * TS) + (size_t)f * 128 + 2 * l;
#pragma unroll 8
        for (int s = 0; s < 64; ++s) {
            float2 v2 = stage[l][s];
            if (act) {
                *reinterpret_cast<float2*>(ob + (size_t)s * (2 * TS)) = v2;
            }
        }

        asm volatile("" ::: "memory");

        wa = na;
        wb = nb;
    }
}

// --- fallback if ws too small: read inp directly (uncoalesced but correct)
__global__ __launch_bounds__(64) void scan_fused(const float* __restrict__ inp,
                                                 const float* __restrict__ alpha_logits,
                                                 const float* __restrict__ gamma_logits,
                                                 const float* __restrict__ k_vals,
                                                 float* __restrict__ out) {
    int b = blockIdx.x * 64 + threadIdx.x;
    const Params P = load_params(alpha_logits, gamma_logits, k_vals);
    float sL = 0.0f, sR = 0.0f, lam = 0.5f;
    float* op = out + (size_t)b * (2 * TS);
    for (int w = 0; w < NW; ++w) {
        const float4* p = reinterpret_cast<const float4*>(inp + (size_t)b * (3 * TS) + (size_t)w * 24);
        float4 q0 = p[0], q1 = p[1], q2 = p[2], q3 = p[3], q4 = p[4], q5 = p[5];
        float c[8] = {q0.x, q0.w, q1.z, q2.y, q3.x, q3.w, q4.z, q5.y};
        float o[8] = {q0.z, q1.y, q2.x, q2.w, q3.z, q4.y, q5.x, q5.w};
#pragma unroll
        for (int i = 0; i < 8; ++i) {
            unsigned j = ((c[i] == 0.0f) ? 2u : 0u) | ((o[i] == 0.0f) ? 1u : 0u);
            reinterpret_cast<float2*>(op)[w * 8 + i] = step1(j, sL, sR, lam, P);
        }
    }
}

extern "C" void kernel_launch(void* const* d_in, const int* in_sizes, int n_in,
                              void* d_out, int out_size, void* d_ws, size_t ws_size,
                              hipStream_t stream) {
    const float* inp          = (const float*)d_in[0];
    const float* alpha_logits = (const float*)d_in[1];
    const float* gamma_logits = (const float*)d_in[2];
    const float* k_vals       = (const float*)d_in[3];
    float* out = (float*)d_out;

    size_t need = (size_t)NG4 * BS * 4 * sizeof(unsigned int); // 2 MiB
    if (ws_size >= need) {
        unsigned int* packed = (unsigned int*)d_ws;
        int total = BS * NW;
        pack_kernel<<<(total + 255) / 256, 256, 0, stream>>>(inp, packed);
        scan3<<<BS / 64, 64, 0, stream>>>((const uint4*)packed, alpha_logits, gamma_logits,
                                          k_vals, out);
    } else {
        scan_fused<<<BS / 64, 64, 0, stream>>>(inp, alpha_logits, gamma_logits, k_vals, out);
    }
}

// Round 4
// 65.197 us; speedup vs baseline: 1.2858x; 1.2858x over previous
//
#include <hip/hip_runtime.h>
#include <hip/hip_bf16.h>

// DynamicQAgent: B=4096 sessions, T=1000 steps. Sequential in T, parallel in B.
//
// R4 structure (R1-R3 lesson: 4096 sessions = 64 waves = 1 wave/SIMD; every
// per-step cost is latency-exposed and ~5x the issue model; stop fighting it,
// add TLP by splitting T):
//   pack: classify each step into 2-bit code j, coalesced (49MB read).
//   ckpt: 64 waves walk the full scan, storing ONLY the state every 32 steps
//         (32 checkpoints/session, 2MB). No output traffic. LDS LUT math.
//   emit: 131072 threads = 2048 waves (2/SIMD): thread (chunk c, session b)
//         restarts from exact checkpoint, recomputes 32 steps, stores float4
//         pairs. Compute ~1us aggregate; bound by 32MB store BW.
// Checkpoints are exact f32 state -> bitwise identical to the serial scan.

constexpr int BS = 4096;     // sessions
constexpr int TS = 1000;     // timesteps
constexpr int NW = 125;      // packed 8-step words per session
constexpr int NG4 = 32;      // uint4 groups per session (128 words, padded)
constexpr int NCH = 32;      // chunks of 32 steps (last chunk = 8 steps)
constexpr int CSTEPS = 32;

__device__ __forceinline__ float sigmoidf_(float x) {
    return 1.0f / (1.0f + expf(-x));
}

struct Params {
    float k0, k1, k2, k3;
    float a0, a1, a2, a3;
    float g0, g1;
};

__device__ __forceinline__ Params load_params(const float* __restrict__ alpha_logits,
                                              const float* __restrict__ gamma_logits,
                                              const float* __restrict__ k_vals) {
    Params P;
    P.a0 = sigmoidf_(alpha_logits[0]);
    P.a1 = sigmoidf_(alpha_logits[1]);
    P.a2 = sigmoidf_(alpha_logits[2]);
    P.a3 = sigmoidf_(alpha_logits[3]);
    P.g0 = sigmoidf_(gamma_logits[0]);
    P.g1 = sigmoidf_(gamma_logits[1]);
    P.k0 = k_vals[0];
    P.k1 = k_vals[1];
    P.k2 = k_vals[2];
    P.k3 = k_vals[3];
    return P;
}

// one scan step; math identical to R1/R2/R3 (absmax-verified)
__device__ __forceinline__ float2 step1(unsigned j, float& sL, float& sR, float& lam,
                                        const Params& P) {
    bool b0 = (j & 1u) != 0u;  // outcome == 0
    bool b1 = (j & 2u) != 0u;  // choice  == 0
    float k_lo = b0 ? P.k1 : P.k0;
    float k_hi = b0 ? P.k3 : P.k2;
    float a_lo = b0 ? P.a1 : P.a0;
    float a_hi = b0 ? P.a3 : P.a2;
    float gb   = b0 ? P.g1 : P.g0;
    float kj   = b1 ? k_hi : k_lo;
    float kjR  = b1 ? k_lo : k_hi;
    float aj   = b1 ? a_hi : a_lo;
    float ajR  = b1 ? a_lo : a_hi;
    float dL = kj - sL;           // old state
    float dR = kjR - sR;
    float v  = b1 ? dR : dL;      // gdiffs[j] = k[j&1] - (j>=2 ? sR : sL)
    sL = fmaf(dL * aj, lam, sL);
    sR = fmaf(dR * ajR, lam, sR);
    lam = fmaf(fabsf(v) - lam, gb, lam);
    return make_float2(sL, sR);
}

// --- pass 1: pack 8 steps (24 floats = 6 float4) into one u32 of 2-bit codes.
// uint4 layout: packed4[(w>>2)*BS + b] holds words 4g..4g+3 of session b.
__global__ __launch_bounds__(256) void pack_kernel(const float* __restrict__ inp,
                                                   unsigned int* __restrict__ packed) {
    int tid = blockIdx.x * blockDim.x + threadIdx.x;
    if (tid >= BS * NW) return;
    int b = tid / NW;
    int w = tid - b * NW;
    const float4* p = reinterpret_cast<const float4*>(inp + (size_t)b * (3 * TS) + (size_t)w * 24);
    float4 q0 = p[0], q1 = p[1], q2 = p[2], q3 = p[3], q4 = p[4], q5 = p[5];
    float c[8] = {q0.x, q0.w, q1.z, q2.y, q3.x, q3.w, q4.z, q5.y};
    float o[8] = {q0.z, q1.y, q2.x, q2.w, q3.z, q4.y, q5.x, q5.w};
    unsigned word = 0;
#pragma unroll
    for (int i = 0; i < 8; ++i) {
        unsigned j = ((c[i] == 0.0f) ? 2u : 0u) | ((o[i] == 0.0f) ? 1u : 0u);
        word |= j << (2 * i);
    }
    packed[(size_t)(w >> 2) * (BS * 4) + (size_t)b * 4 + (w & 3)] = word;
}

// --- pass 2: serial checkpoint walk. 64 blocks x 64 threads, thread=session.
// Stores state BEFORE chunk c for c=0..31; processes words 0..123 (992 steps).
__global__ __launch_bounds__(64) void ckpt_kernel(const uint4* __restrict__ packed4,
                                                  const float* __restrict__ alpha_logits,
                                                  const float* __restrict__ gamma_logits,
                                                  const float* __restrict__ k_vals,
                                                  float4* __restrict__ ckpt) {
    __shared__ float lut[4][8];  // row j: k[j], k[j^2], a[j], a[j^2], g[j&1]
    const int l = threadIdx.x;
    const int b = blockIdx.x * 64 + l;

    if (l < 4) {
        float kk[4] = {k_vals[0], k_vals[1], k_vals[2], k_vals[3]};
        float aa[4] = {sigmoidf_(alpha_logits[0]), sigmoidf_(alpha_logits[1]),
                       sigmoidf_(alpha_logits[2]), sigmoidf_(alpha_logits[3])};
        float gg[2] = {sigmoidf_(gamma_logits[0]), sigmoidf_(gamma_logits[1])};
        lut[l][0] = kk[l];
        lut[l][1] = kk[l ^ 2];
        lut[l][2] = aa[l];
        lut[l][3] = aa[l ^ 2];
        lut[l][4] = gg[l & 1];
    }
    __syncthreads();

    float sL = 0.0f, sR = 0.0f, lam = 0.5f;
    const uint4* pp = packed4 + b;
    uint4 cur = pp[0];

    for (int c = 0; c < NCH; ++c) {
        ckpt[(size_t)c * BS + b] = make_float4(sL, sR, lam, 0.0f);
        if (c == NCH - 1) break;                 // chunk 31 not walked here
        uint4 nxt = pp[(size_t)(c + 1) * BS];    // prefetch next group
        const unsigned words[4] = {cur.x, cur.y, cur.z, cur.w};
#pragma unroll
        for (int q = 0; q < 4; ++q) {
            unsigned w = words[q];
#pragma unroll
            for (int i = 0; i < 8; ++i) {
                unsigned j = (w >> (2 * i)) & 3u;
                const float4 e = *reinterpret_cast<const float4*>(&lut[j][0]);
                const float gb = lut[j][4];
                float dL = e.x - sL;
                float dR = e.y - sR;
                float v = (j >= 2u) ? dR : dL;
                sL = fmaf(dL * e.z, lam, sL);
                sR = fmaf(dR * e.w, lam, sR);
                lam = fmaf(fabsf(v) - lam, gb, lam);
            }
        }
        cur = nxt;
    }
}

// --- pass 3: parallel emit. thread = (chunk c, session b); 512 blocks x 256.
__global__ __launch_bounds__(256) void emit_kernel(const uint4* __restrict__ packed4,
                                                   const float4* __restrict__ ckpt,
                                                   const float* __restrict__ alpha_logits,
                                                   const float* __restrict__ gamma_logits,
                                                   const float* __restrict__ k_vals,
                                                   float* __restrict__ out) {
    int tid = blockIdx.x * 256 + threadIdx.x;
    int c = tid >> 12;        // /4096  (block-uniform)
    int b = tid & 4095;
    const Params P = load_params(alpha_logits, gamma_logits, k_vals);

    float4 st = ckpt[(size_t)c * BS + b];        // coalesced
    float sL = st.x, sR = st.y, lam = st.z;
    uint4 cw = packed4[(size_t)c * BS + b];      // coalesced
    const unsigned words[4] = {cw.x, cw.y, cw.z, cw.w};

    float* ob = out + (size_t)b * (2 * TS) + (size_t)c * (2 * CSTEPS);
    const int nq = (c == NCH - 1) ? 1 : 4;       // last chunk = 8 steps

    for (int q = 0; q < nq; ++q) {
        unsigned w = words[q];
#pragma unroll
        for (int i = 0; i < 8; i += 2) {
            float2 r0 = step1((w >> (2 * i)) & 3u, sL, sR, lam, P);
            float2 r1 = step1((w >> (2 * i + 2)) & 3u, sL, sR, lam, P);
            *reinterpret_cast<float4*>(ob + q * 16 + i * 2) =
                make_float4(r0.x, r0.y, r1.x, r1.y);
        }
    }
}

// --- fallback if ws too small: read inp directly (uncoalesced but correct)
__global__ __launch_bounds__(64) void scan_fused(const float* __restrict__ inp,
                                                 const float* __restrict__ alpha_logits,
                                                 const float* __restrict__ gamma_logits,
                                                 const float* __restrict__ k_vals,
                                                 float* __restrict__ out) {
    int b = blockIdx.x * 64 + threadIdx.x;
    const Params P = load_params(alpha_logits, gamma_logits, k_vals);
    float sL = 0.0f, sR = 0.0f, lam = 0.5f;
    float* op = out + (size_t)b * (2 * TS);
    for (int w = 0; w < NW; ++w) {
        const float4* p = reinterpret_cast<const float4*>(inp + (size_t)b * (3 * TS) + (size_t)w * 24);
        float4 q0 = p[0], q1 = p[1], q2 = p[2], q3 = p[3], q4 = p[4], q5 = p[5];
        float c[8] = {q0.x, q0.w, q1.z, q2.y, q3.x, q3.w, q4.z, q5.y};
        float o[8] = {q0.z, q1.y, q2.x, q2.w, q3.z, q4.y, q5.x, q5.w};
#pragma unroll
        for (int i = 0; i < 8; ++i) {
            unsigned j = ((c[i] == 0.0f) ? 2u : 0u) | ((o[i] == 0.0f) ? 1u : 0u);
            reinterpret_cast<float2*>(op)[w * 8 + i] = step1(j, sL, sR, lam, P);
        }
    }
}

extern "C" void kernel_launch(void* const* d_in, const int* in_sizes, int n_in,
                              void* d_out, int out_size, void* d_ws, size_t ws_size,
                              hipStream_t stream) {
    const float* inp          = (const float*)d_in[0];
    const float* alpha_logits = (const float*)d_in[1];
    const float* gamma_logits = (const float*)d_in[2];
    const float* k_vals       = (const float*)d_in[3];
    float* out = (float*)d_out;

    const size_t packedB = (size_t)NG4 * BS * 4 * sizeof(unsigned int);  // 2 MiB
    const size_t ckptB   = (size_t)NCH * BS * sizeof(float4);            // 2 MiB

    if (ws_size >= packedB + ckptB) {
        unsigned int* packed = (unsigned int*)d_ws;
        float4* ckpt = (float4*)((char*)d_ws + packedB);
        int total = BS * NW;
        pack_kernel<<<(total + 255) / 256, 256, 0, stream>>>(inp, packed);
        ckpt_kernel<<<BS / 64, 64, 0, stream>>>((const uint4*)packed, alpha_logits,
                                                gamma_logits, k_vals, ckpt);
        emit_kernel<<<(NCH * BS) / 256, 256, 0, stream>>>((const uint4*)packed, ckpt,
                                                          alpha_logits, gamma_logits,
                                                          k_vals, out);
    } else {
        scan_fused<<<BS / 64, 64, 0, stream>>>(inp, alpha_logits, gamma_logits, k_vals, out);
    }
}